// Round 1
// baseline (603.695 us; speedup 1.0000x reference)
//
#include <hip/hip_runtime.h>
#include <cmath>

#define HH 96
#define WW 96
#define HWsz 9216
#define BB 4
#define CCH 256
#define OO 256
#define MTOT 36864
#define NTAP 9

using short8 = __attribute__((ext_vector_type(8))) short;
using f32x4  = __attribute__((ext_vector_type(4))) float;

__device__ __forceinline__ unsigned short f2bf(float f) {
    unsigned u = __float_as_uint(f);
    u += 0x7fff + ((u >> 16) & 1);
    return (unsigned short)(u >> 16);
}

// ---------------- prep: weight permute/convert + plain table + BN fold ----------------
// wpB  [256][9][256] bf16  : wpB[((o*9+t)*256+c)] = bf16(w[(o*256+c)*9+t])
// wpA  [32][9][256]  bf16  : rows >=27 zero
// tpi/tpw [36864*9]        : plain-conv gather (zero-pad validity)
// sc2/sh2 [256]            : BN scale / (beta - rmean*scale + bias*scale)
__global__ __launch_bounds__(256) void prep_kernel(
    const float* __restrict__ w, const float* __restrict__ w_off,
    const float* __restrict__ gamma, const float* __restrict__ beta,
    const float* __restrict__ rmean, const float* __restrict__ rvar,
    const float* __restrict__ bconv,
    unsigned short* __restrict__ wpB, unsigned short* __restrict__ wpA,
    int* __restrict__ tpi, float* __restrict__ tpw,
    float* __restrict__ sc2, float* __restrict__ sh2)
{
    int gid = blockIdx.x * 256 + threadIdx.x;
    if (gid < 589824) {
        int c = gid & 255, ot = gid >> 8;
        int t = ot % 9, o = ot / 9;
        wpB[gid] = f2bf(w[(o * 256 + c) * 9 + t]);
        return;
    }
    gid -= 589824;
    if (gid < 73728) {
        int c = gid & 255, ot = gid >> 8;
        int t = ot % 9, o = ot / 9;
        wpA[gid] = (o < 27) ? f2bf(w_off[(o * 256 + c) * 9 + t]) : (unsigned short)0;
        return;
    }
    gid -= 73728;
    if (gid < 331776) {
        int p = gid / 9, t = gid - p * 9;
        int hw = p % HWsz;
        int h = hw / WW, x = hw % WW;
        int yy = h + t / 3 - 1, xx = x + t % 3 - 1;
        bool v = (yy >= 0) && (yy < HH) && (xx >= 0) && (xx < WW);
        tpi[gid] = v ? yy * WW + xx : 0;
        tpw[gid] = v ? 1.f : 0.f;
        return;
    }
    gid -= 331776;
    if (gid < 256) {
        float s = gamma[gid] * rsqrtf(rvar[gid] + 1e-5f);
        sc2[gid] = s;
        sh2[gid] = beta[gid] - rmean[gid] * s + bconv[gid] * s;
    }
}

// ---------------- build deform table from offset-conv output ----------------
// off layout [b][32][HW] (channels 0..26 valid): dy=ch 2t, dx=ch 2t+1, mask=sigmoid(ch 18+t)
__global__ __launch_bounds__(256) void build_table(
    const float* __restrict__ off, int* __restrict__ tbi, float* __restrict__ tbw)
{
    int e = blockIdx.x * 256 + threadIdx.x;
    if (e >= MTOT * NTAP) return;
    int p = e / 9, t = e - p * 9;
    int b = p / HWsz, hw = p - b * HWsz;
    int h = hw / WW, x = hw % WW;
    const float* ob = off + ((size_t)b * 32) * HWsz + hw;
    float dy = ob[(2 * t) * HWsz];
    float dx = ob[(2 * t + 1) * HWsz];
    float ml = ob[(18 + t) * HWsz];
    float m = 1.f / (1.f + __expf(-ml));
    float py = (float)(h + t / 3 - 1) + dy;
    float px = (float)(x + t % 3 - 1) + dx;
    float y0f = floorf(py), x0f = floorf(px);
    float ly = py - y0f, lx = px - x0f;
    int y0 = (int)y0f, x0 = (int)x0f;
    int y1 = y0 + 1, x1 = x0 + 1;
    bool vy0 = (y0 >= 0) && (y0 <= HH - 1), vy1 = (y1 >= 0) && (y1 <= HH - 1);
    bool vx0 = (x0 >= 0) && (x0 <= WW - 1), vx1 = (x1 >= 0) && (x1 <= WW - 1);
    int yc0 = min(max(y0, 0), HH - 1), yc1 = min(max(y1, 0), HH - 1);
    int xc0 = min(max(x0, 0), WW - 1), xc1 = min(max(x1, 0), WW - 1);
    float w00 = (1.f - ly) * (1.f - lx) * m;
    float w01 = (1.f - ly) * lx * m;
    float w10 = ly * (1.f - lx) * m;
    float w11 = ly * lx * m;
    int4 iv; iv.x = yc0 * WW + xc0; iv.y = yc0 * WW + xc1; iv.z = yc1 * WW + xc0; iv.w = yc1 * WW + xc1;
    float4 wv;
    wv.x = (vy0 && vx0) ? w00 : 0.f;
    wv.y = (vy0 && vx1) ? w01 : 0.f;
    wv.z = (vy1 && vx0) ? w10 : 0.f;
    wv.w = (vy1 && vx1) ? w11 : 0.f;
    ((int4*)tbi)[e] = iv;
    ((float4*)tbw)[e] = wv;
}

// ---------------- implicit GEMM: gather(A) x wperm(B) with MFMA bf16 ----------------
// M-tile = 64 pixels per block. NOCH = full N (32 for offset pass, 256 for main).
// 4 waves: mslab = wid % (4/WM), nslab = wid / (4/WM).
template<int NOCH, int NCOR, int WM, int WN, bool PASS2>
__global__ __launch_bounds__(256) void gemm_dcn(
    const float* __restrict__ x,
    const unsigned short* __restrict__ wperm,
    const int* __restrict__ tbi, const float* __restrict__ tbw,
    const float* __restrict__ ep0, const float* __restrict__ ep1,
    float* __restrict__ outp)
{
    constexpr int NWM = 4 / WM;
    __shared__ unsigned short Alds[64][40];   // [px][k] pad to 40 (80B rows)
    __shared__ unsigned short Blds[NOCH][40];

    const int tid  = threadIdx.x;
    const int wid  = tid >> 6;
    const int lane = tid & 63;
    const int l15  = lane & 15;
    const int kh   = lane >> 4;           // k-block 0..3
    const int mslab = wid % NWM;
    const int nslab = wid / NWM;

    const int p0  = blockIdx.x * 64;
    const int sp  = tid >> 2;             // staging pixel 0..63
    const int scg = tid & 3;              // c sub-group (8 ch each)
    const int pg  = p0 + sp;
    const int img = pg / HWsz;            // uniform per block (9216 % 64 == 0)
    const float* __restrict__ xim = x + (size_t)img * CCH * HWsz;

    f32x4 acc[WM][WN];
    #pragma unroll
    for (int m = 0; m < WM; ++m)
        #pragma unroll
        for (int n = 0; n < WN; ++n)
            acc[m][n] = f32x4{0.f, 0.f, 0.f, 0.f};

    for (int t = 0; t < NTAP; ++t) {
        int ti0 = 0, ti1 = 0, ti2 = 0, ti3 = 0;
        float tw0 = 0.f, tw1 = 0.f, tw2 = 0.f, tw3 = 0.f;
        if constexpr (NCOR == 4) {
            int4 iv = ((const int4*)tbi)[pg * NTAP + t];
            float4 wv = ((const float4*)tbw)[pg * NTAP + t];
            ti0 = iv.x; ti1 = iv.y; ti2 = iv.z; ti3 = iv.w;
            tw0 = wv.x; tw1 = wv.y; tw2 = wv.z; tw3 = wv.w;
        } else {
            ti0 = tbi[pg * NTAP + t];
            tw0 = tbw[pg * NTAP + t];
        }
        for (int cc = 0; cc < 8; ++cc) {
            // ---- A stage: val for 8 channels, this (pixel, tap) ----
            const unsigned cbase = (unsigned)(cc * 32 + scg * 8) * HWsz;
            short8 pk;
            #pragma unroll
            for (int i = 0; i < 8; ++i) {
                unsigned o = cbase + (unsigned)i * HWsz;
                float v;
                if constexpr (NCOR == 4) {
                    v = tw0 * xim[o + ti0] + tw1 * xim[o + ti1]
                      + tw2 * xim[o + ti2] + tw3 * xim[o + ti3];
                } else {
                    v = tw0 * xim[o + ti0];
                }
                pk[i] = (short)f2bf(v);
            }
            *(short8*)&Alds[sp][scg * 8] = pk;
            // ---- B stage ----
            if constexpr (NOCH == 256) {
                #pragma unroll
                for (int r = 0; r < 4; ++r) {
                    int s = tid + r * 256;
                    int o = s >> 2, q = s & 3;
                    short8 v = *(const short8*)(wperm + (size_t)(o * NTAP + t) * 256 + cc * 32 + q * 8);
                    *(short8*)&Blds[o][q * 8] = v;
                }
            } else {
                if (tid < NOCH * 4) {
                    int o = tid >> 2, q = tid & 3;
                    short8 v = *(const short8*)(wperm + (size_t)(o * NTAP + t) * 256 + cc * 32 + q * 8);
                    *(short8*)&Blds[o][q * 8] = v;
                }
            }
            __syncthreads();
            // ---- MFMA ----
            short8 af[WM], bfr[WN];
            #pragma unroll
            for (int m = 0; m < WM; ++m)
                af[m] = *(const short8*)&Alds[mslab * WM * 16 + m * 16 + l15][kh * 8];
            #pragma unroll
            for (int n = 0; n < WN; ++n)
                bfr[n] = *(const short8*)&Blds[nslab * WN * 16 + n * 16 + l15][kh * 8];
            #pragma unroll
            for (int m = 0; m < WM; ++m)
                #pragma unroll
                for (int n = 0; n < WN; ++n)
                    acc[m][n] = __builtin_amdgcn_mfma_f32_16x16x32_bf16(af[m], bfr[n], acc[m][n], 0, 0, 0);
            __syncthreads();
        }
    }
    // ---- epilogue ----
    #pragma unroll
    for (int n = 0; n < WN; ++n) {
        int och = nslab * WN * 16 + n * 16 + l15;
        float s0 = 0.f, s1 = 0.f;
        if constexpr (PASS2) { s0 = ep0[och]; s1 = ep1[och]; }
        else { s1 = (och < 27) ? ep0[och] : 0.f; }
        #pragma unroll
        for (int m = 0; m < WM; ++m) {
            #pragma unroll
            for (int j = 0; j < 4; ++j) {
                int pr = p0 + mslab * WM * 16 + m * 16 + kh * 4 + j;
                int ohw = pr - img * HWsz;
                float v = acc[m][n][j];
                if constexpr (PASS2) {
                    v = fmaxf(fmaf(v, s0, s1), 0.f);
                    outp[((size_t)img * OO + och) * HWsz + ohw] = v;
                } else {
                    if (och < 27)
                        outp[((size_t)img * 32 + och) * HWsz + ohw] = v + s1;
                }
            }
        }
    }
}

extern "C" void kernel_launch(void* const* d_in, const int* in_sizes, int n_in,
                              void* d_out, int out_size, void* d_ws, size_t ws_size,
                              hipStream_t stream) {
    const float* input_x = (const float*)d_in[0];
    const float* w_off   = (const float*)d_in[1];
    const float* b_off   = (const float*)d_in[2];
    const float* w       = (const float*)d_in[3];
    const float* b       = (const float*)d_in[4];
    const float* gamma   = (const float*)d_in[5];
    const float* beta    = (const float*)d_in[6];
    const float* rmean   = (const float*)d_in[7];
    const float* rvar    = (const float*)d_in[8];
    float* out = (float*)d_out;

    char* p = (char*)d_ws;
    auto alloc = [&](size_t bytes) {
        char* r = p;
        p += (bytes + 255) & ~(size_t)255;
        return r;
    };
    unsigned short* wpB = (unsigned short*)alloc(589824 * 2);
    unsigned short* wpA = (unsigned short*)alloc(73728 * 2);
    int*   tpi = (int*)alloc(331776 * 4);
    float* tpw = (float*)alloc(331776 * 4);
    int*   tdi = (int*)alloc(331776 * 16);
    float* tdw = (float*)alloc(331776 * 16);
    float* offb = (float*)alloc((size_t)4 * 32 * 9216 * 4);
    float* sc2 = (float*)alloc(256 * 4);
    float* sh2 = (float*)alloc(256 * 4);

    prep_kernel<<<3889, 256, 0, stream>>>(w, w_off, gamma, beta, rmean, rvar, b,
                                          wpB, wpA, tpi, tpw, sc2, sh2);
    gemm_dcn<32, 1, 1, 2, false><<<576, 256, 0, stream>>>(input_x, wpA, tpi, tpw, b_off, nullptr, offb);
    build_table<<<1296, 256, 0, stream>>>(offb, tdi, tdw);
    gemm_dcn<256, 4, 4, 4, true><<<576, 256, 0, stream>>>(input_x, wpB, tdi, tdw, sc2, sh2, out);
}

// Round 3
// 554.617 us; speedup vs baseline: 1.0885x; 1.0885x over previous
//
#include <hip/hip_runtime.h>
#include <cmath>

#define HH 96
#define WW 96
#define HWsz 9216
#define CCH 256
#define OO 256
#define MTOT 36864
#define NTAP 9

using short8 = __attribute__((ext_vector_type(8))) short;
using f32x4  = __attribute__((ext_vector_type(4))) float;

__device__ __forceinline__ unsigned short f2bf(float f) {
    unsigned u = __float_as_uint(f);
    u += 0x7fff + ((u >> 16) & 1);
    return (unsigned short)(u >> 16);
}

// ---------------- prep: weight permute/convert + plain table + BN fold ----------------
__global__ __launch_bounds__(256) void prep_kernel(
    const float* __restrict__ w, const float* __restrict__ w_off,
    const float* __restrict__ gamma, const float* __restrict__ beta,
    const float* __restrict__ rmean, const float* __restrict__ rvar,
    const float* __restrict__ bconv,
    unsigned short* __restrict__ wpB, unsigned short* __restrict__ wpA,
    int* __restrict__ tpi, float* __restrict__ tpw,
    float* __restrict__ sc2, float* __restrict__ sh2)
{
    int gid = blockIdx.x * 256 + threadIdx.x;
    if (gid < 589824) {
        int c = gid & 255, ot = gid >> 8;
        int t = ot % 9, o = ot / 9;
        wpB[gid] = f2bf(w[(o * 256 + c) * 9 + t]);
        return;
    }
    gid -= 589824;
    if (gid < 73728) {
        int c = gid & 255, ot = gid >> 8;
        int t = ot % 9, o = ot / 9;
        wpA[gid] = (o < 27) ? f2bf(w_off[(o * 256 + c) * 9 + t]) : (unsigned short)0;
        return;
    }
    gid -= 73728;
    if (gid < 331776) {
        int p = gid / 9, t = gid - p * 9;
        int hw = p % HWsz;
        int h = hw / WW, x = hw % WW;
        int yy = h + t / 3 - 1, xx = x + t % 3 - 1;
        bool v = (yy >= 0) && (yy < HH) && (xx >= 0) && (xx < WW);
        tpi[gid] = v ? yy * WW + xx : 0;
        tpw[gid] = v ? 1.f : 0.f;
        return;
    }
    gid -= 331776;
    if (gid < 256) {
        float s = gamma[gid] * rsqrtf(rvar[gid] + 1e-5f);
        sc2[gid] = s;
        sh2[gid] = beta[gid] - rmean[gid] * s + bconv[gid] * s;
    }
}

// ---------------- build deform table from offset-conv output ----------------
__global__ __launch_bounds__(256) void build_table(
    const float* __restrict__ off, int* __restrict__ tbi, float* __restrict__ tbw)
{
    int e = blockIdx.x * 256 + threadIdx.x;
    if (e >= MTOT * NTAP) return;
    int p = e / 9, t = e - p * 9;
    int b = p / HWsz, hw = p - b * HWsz;
    int h = hw / WW, x = hw % WW;
    const float* ob = off + ((size_t)b * 32) * HWsz + hw;
    float dy = ob[(2 * t) * HWsz];
    float dx = ob[(2 * t + 1) * HWsz];
    float ml = ob[(18 + t) * HWsz];
    float m = 1.f / (1.f + __expf(-ml));
    float py = (float)(h + t / 3 - 1) + dy;
    float px = (float)(x + t % 3 - 1) + dx;
    float y0f = floorf(py), x0f = floorf(px);
    float ly = py - y0f, lx = px - x0f;
    int y0 = (int)y0f, x0 = (int)x0f;
    int y1 = y0 + 1, x1 = x0 + 1;
    bool vy0 = (y0 >= 0) && (y0 <= HH - 1), vy1 = (y1 >= 0) && (y1 <= HH - 1);
    bool vx0 = (x0 >= 0) && (x0 <= WW - 1), vx1 = (x1 >= 0) && (x1 <= WW - 1);
    int yc0 = min(max(y0, 0), HH - 1), yc1 = min(max(y1, 0), HH - 1);
    int xc0 = min(max(x0, 0), WW - 1), xc1 = min(max(x1, 0), WW - 1);
    float w00 = (1.f - ly) * (1.f - lx) * m;
    float w01 = (1.f - ly) * lx * m;
    float w10 = ly * (1.f - lx) * m;
    float w11 = ly * lx * m;
    int4 iv; iv.x = yc0 * WW + xc0; iv.y = yc0 * WW + xc1; iv.z = yc1 * WW + xc0; iv.w = yc1 * WW + xc1;
    float4 wv;
    wv.x = (vy0 && vx0) ? w00 : 0.f;
    wv.y = (vy0 && vx1) ? w01 : 0.f;
    wv.z = (vy1 && vx0) ? w10 : 0.f;
    wv.w = (vy1 && vx1) ? w11 : 0.f;
    ((int4*)tbi)[e] = iv;
    ((float4*)tbw)[e] = wv;
}

// ---------------- implicit GEMM with register-prefetch pipeline ----------------
// M-tile = 64 pixels/block, chunked-XCD-swizzled. One raw s_barrier per K-step,
// LDS double-buffered; iter i+1's gather + B loads issued before the barrier and
// stay in flight across it (no vmcnt drain).
template<int NOCH, int NCOR, int WM, int WN, bool PASS2>
__global__ __launch_bounds__(256, 3) void gemm_dcn(
    const float* __restrict__ x,
    const unsigned short* __restrict__ wperm,
    const int* __restrict__ tbi, const float* __restrict__ tbw,
    const float* __restrict__ ep0, const float* __restrict__ ep1,
    float* __restrict__ outp)
{
    constexpr int NWM = 4 / WM;
    constexpr int NB  = (NOCH == 256) ? 4 : 1;
    __shared__ __align__(16) unsigned short Alds[2][64][40];
    __shared__ __align__(16) unsigned short Blds[2][NOCH][40];

    const int tid  = threadIdx.x;
    const int wid  = tid >> 6;
    const int lane = tid & 63;
    const int l15  = lane & 15;
    const int kh   = lane >> 4;
    const int mslab = wid % NWM;
    const int nslab = wid / NWM;

    // chunked XCD swizzle: same-XCD blocks get consecutive M-strips
    const int bid = blockIdx.x;
    const int mblk = (bid & 7) * ((int)gridDim.x >> 3) + (bid >> 3);
    const int p0  = mblk * 64;

    const int sp  = tid >> 2;
    const int scg = tid & 3;
    const int pg  = p0 + sp;
    const int img = pg / HWsz;
    const float* __restrict__ xim = x + (size_t)img * CCH * HWsz;

    f32x4 acc[WM][WN];
    #pragma unroll
    for (int m = 0; m < WM; ++m)
        #pragma unroll
        for (int n = 0; n < WN; ++n)
            acc[m][n] = f32x4{0.f, 0.f, 0.f, 0.f};

    // pipeline state registers
    int ti0 = 0, ti1 = 0, ti2 = 0, ti3 = 0;
    float tw0 = 0.f, tw1 = 0.f, tw2 = 0.f, tw3 = 0.f;
    float xv0[8], xv1[8], xv2[8], xv3[8];
    short8 bv[NB];

    auto LOADTAB = [&](int t) {
        if constexpr (NCOR == 4) {
            int4 iv = ((const int4*)tbi)[pg * NTAP + t];
            float4 wv = ((const float4*)tbw)[pg * NTAP + t];
            ti0 = iv.x; ti1 = iv.y; ti2 = iv.z; ti3 = iv.w;
            tw0 = wv.x; tw1 = wv.y; tw2 = wv.z; tw3 = wv.w;
        } else {
            ti0 = tbi[pg * NTAP + t];
            tw0 = tbw[pg * NTAP + t];
        }
    };

    auto PRELOAD = [&](int t, int cc) {
        const unsigned cbase = (unsigned)(cc * 32 + scg * 8) * HWsz;
        const float* __restrict__ b0 = xim + ti0;
        const float* __restrict__ b1 = xim + ti1;
        const float* __restrict__ b2 = xim + ti2;
        const float* __restrict__ b3 = xim + ti3;
        #pragma unroll
        for (int i = 0; i < 8; ++i) {
            unsigned o = cbase + (unsigned)i * HWsz;
            xv0[i] = b0[o];
            if constexpr (NCOR == 4) {
                xv1[i] = b1[o];
                xv2[i] = b2[o];
                xv3[i] = b3[o];
            }
        }
        if constexpr (NOCH == 256) {
            #pragma unroll
            for (int r = 0; r < 4; ++r) {
                int s = tid + r * 256;
                int o = s >> 2, q = s & 3;
                bv[r] = *(const short8*)(wperm + (size_t)(o * NTAP + t) * 256 + cc * 32 + q * 8);
            }
        } else {
            if (tid < NOCH * 4) {
                int o = tid >> 2, q = tid & 3;
                bv[0] = *(const short8*)(wperm + (size_t)(o * NTAP + t) * 256 + cc * 32 + q * 8);
            }
        }
    };

    auto PACK = [&](int buf) {
        short8 pk;
        #pragma unroll
        for (int i = 0; i < 8; ++i) {
            float v = tw0 * xv0[i];
            if constexpr (NCOR == 4)
                v += tw1 * xv1[i] + tw2 * xv2[i] + tw3 * xv3[i];
            pk[i] = (short)f2bf(v);
        }
        *(short8*)&Alds[buf][sp][scg * 8] = pk;
        if constexpr (NOCH == 256) {
            #pragma unroll
            for (int r = 0; r < 4; ++r) {
                int s = tid + r * 256;
                int o = s >> 2, q = s & 3;
                *(short8*)&Blds[buf][o][q * 8] = bv[r];
            }
        } else {
            if (tid < NOCH * 4) {
                int o = tid >> 2, q = tid & 3;
                *(short8*)&Blds[buf][o][q * 8] = bv[0];
            }
        }
    };

    LOADTAB(0);
    PRELOAD(0, 0);
    int buf = 0;
    for (int it = 0; it < NTAP * 8; ++it) {
        PACK(buf);
        int nit = it + 1;
        if (nit < NTAP * 8) {
            int nt = nit >> 3, ncc = nit & 7;
            if (ncc == 0) LOADTAB(nt);
            PRELOAD(nt, ncc);
        }
        // drain only LDS writes; prefetch global loads stay in flight across barrier
        asm volatile("s_waitcnt lgkmcnt(0)" ::: "memory");
        __builtin_amdgcn_s_barrier();
        __builtin_amdgcn_sched_barrier(0);
        short8 af[WM], bfr[WN];
        #pragma unroll
        for (int m = 0; m < WM; ++m)
            af[m] = *(const short8*)&Alds[buf][mslab * WM * 16 + m * 16 + l15][kh * 8];
        #pragma unroll
        for (int n = 0; n < WN; ++n)
            bfr[n] = *(const short8*)&Blds[buf][nslab * WN * 16 + n * 16 + l15][kh * 8];
        #pragma unroll
        for (int m = 0; m < WM; ++m)
            #pragma unroll
            for (int n = 0; n < WN; ++n)
                acc[m][n] = __builtin_amdgcn_mfma_f32_16x16x32_bf16(af[m], bfr[n], acc[m][n], 0, 0, 0);
        buf ^= 1;
    }

    // ---- epilogue ----
    #pragma unroll
    for (int n = 0; n < WN; ++n) {
        int och = nslab * WN * 16 + n * 16 + l15;
        float s0 = 0.f, s1 = 0.f;
        if constexpr (PASS2) { s0 = ep0[och]; s1 = ep1[och]; }
        else { s1 = (och < 27) ? ep0[och] : 0.f; }
        #pragma unroll
        for (int m = 0; m < WM; ++m) {
            #pragma unroll
            for (int j = 0; j < 4; ++j) {
                int pr = p0 + mslab * WM * 16 + m * 16 + kh * 4 + j;
                int ohw = pr - img * HWsz;
                float v = acc[m][n][j];
                if constexpr (PASS2) {
                    v = fmaxf(fmaf(v, s0, s1), 0.f);
                    outp[((size_t)img * OO + och) * HWsz + ohw] = v;
                } else {
                    if (och < 27)
                        outp[((size_t)img * 32 + och) * HWsz + ohw] = v + s1;
                }
            }
        }
    }
}

extern "C" void kernel_launch(void* const* d_in, const int* in_sizes, int n_in,
                              void* d_out, int out_size, void* d_ws, size_t ws_size,
                              hipStream_t stream) {
    const float* input_x = (const float*)d_in[0];
    const float* w_off   = (const float*)d_in[1];
    const float* b_off   = (const float*)d_in[2];
    const float* w       = (const float*)d_in[3];
    const float* b       = (const float*)d_in[4];
    const float* gamma   = (const float*)d_in[5];
    const float* beta    = (const float*)d_in[6];
    const float* rmean   = (const float*)d_in[7];
    const float* rvar    = (const float*)d_in[8];
    float* out = (float*)d_out;

    char* p = (char*)d_ws;
    auto alloc = [&](size_t bytes) {
        char* r = p;
        p += (bytes + 255) & ~(size_t)255;
        return r;
    };
    unsigned short* wpB = (unsigned short*)alloc(589824 * 2);
    unsigned short* wpA = (unsigned short*)alloc(73728 * 2);
    int*   tpi = (int*)alloc(331776 * 4);
    float* tpw = (float*)alloc(331776 * 4);
    int*   tdi = (int*)alloc(331776 * 16);
    float* tdw = (float*)alloc(331776 * 16);
    float* offb = (float*)alloc((size_t)4 * 32 * 9216 * 4);
    float* sc2 = (float*)alloc(256 * 4);
    float* sh2 = (float*)alloc(256 * 4);

    prep_kernel<<<3889, 256, 0, stream>>>(w, w_off, gamma, beta, rmean, rvar, b,
                                          wpB, wpA, tpi, tpw, sc2, sh2);
    gemm_dcn<32, 1, 1, 2, false><<<576, 256, 0, stream>>>(input_x, wpA, tpi, tpw, b_off, nullptr, offb);
    build_table<<<1296, 256, 0, stream>>>(offb, tdi, tdw);
    gemm_dcn<256, 4, 4, 4, true><<<576, 256, 0, stream>>>(input_x, wpB, tdi, tdw, sc2, sh2, out);
}

// Round 4
// 500.244 us; speedup vs baseline: 1.2068x; 1.1087x over previous
//
#include <hip/hip_runtime.h>
#include <cmath>

#define HH 96
#define WW 96
#define HWsz 9216
#define CCH 256
#define OO 256
#define MTOT 36864
#define NTAP 9

using short8 = __attribute__((ext_vector_type(8))) short;
using f32x4  = __attribute__((ext_vector_type(4))) float;

__device__ __forceinline__ unsigned short f2bf(float f) {
    unsigned u = __float_as_uint(f);
    u += 0x7fff + ((u >> 16) & 1);
    return (unsigned short)(u >> 16);
}

// ---------------- prep ----------------
// wq  [t][cc][kh][o=256][j=8] bf16 : element = w[o][c=cc*32+kh*8+j][t]  (B-fragment-direct layout)
// wqA [t][cc][kh][o=32][j=8]  bf16 : o>=27 zero, from w_off
// sc2/sh2 [256] : BN scale / shift(+bias)
__global__ __launch_bounds__(256) void prep_kernel(
    const float* __restrict__ w, const float* __restrict__ w_off,
    const float* __restrict__ gamma, const float* __restrict__ beta,
    const float* __restrict__ rmean, const float* __restrict__ rvar,
    const float* __restrict__ bconv,
    unsigned short* __restrict__ wq, unsigned short* __restrict__ wqA,
    float* __restrict__ sc2, float* __restrict__ sh2)
{
    int gid = blockIdx.x * 256 + threadIdx.x;
    if (gid < 589824) {
        int j = gid & 7, o = (gid >> 3) & 255, kh = (gid >> 11) & 3;
        int cc = (gid >> 13) & 7, t = gid >> 16;
        int c = cc * 32 + kh * 8 + j;
        wq[gid] = f2bf(w[(o * 256 + c) * 9 + t]);
        return;
    }
    gid -= 589824;
    if (gid < 73728) {
        int j = gid & 7, o = (gid >> 3) & 31, kh = (gid >> 8) & 3;
        int cc = (gid >> 10) & 7, t = gid >> 13;
        int c = cc * 32 + kh * 8 + j;
        wqA[gid] = (o < 27) ? f2bf(w_off[(o * 256 + c) * 9 + t]) : (unsigned short)0;
        return;
    }
    gid -= 73728;
    if (gid < 256) {
        float s = gamma[gid] * rsqrtf(rvar[gid] + 1e-5f);
        sc2[gid] = s;
        sh2[gid] = beta[gid] - rmean[gid] * s + bconv[gid] * s;
    }
}

// ---------------- build deform table (SoA: [tap][pixel]) ----------------
__global__ __launch_bounds__(256) void build_table(
    const float* __restrict__ off, int4* __restrict__ tbi, float4* __restrict__ tbw)
{
    int e = blockIdx.x * 256 + threadIdx.x;
    if (e >= MTOT * NTAP) return;
    int p = e / 9, t = e - p * 9;
    int b = p / HWsz, hw = p - b * HWsz;
    int h = hw / WW, x = hw % WW;
    const float* ob = off + ((size_t)b * 32) * HWsz + hw;
    float dy = ob[(2 * t) * HWsz];
    float dx = ob[(2 * t + 1) * HWsz];
    float ml = ob[(18 + t) * HWsz];
    float m = 1.f / (1.f + __expf(-ml));
    float py = (float)(h + t / 3 - 1) + dy;
    float px = (float)(x + t % 3 - 1) + dx;
    float y0f = floorf(py), x0f = floorf(px);
    float ly = py - y0f, lx = px - x0f;
    int y0 = (int)y0f, x0 = (int)x0f;
    int y1 = y0 + 1, x1 = x0 + 1;
    bool vy0 = (y0 >= 0) && (y0 <= HH - 1), vy1 = (y1 >= 0) && (y1 <= HH - 1);
    bool vx0 = (x0 >= 0) && (x0 <= WW - 1), vx1 = (x1 >= 0) && (x1 <= WW - 1);
    int yc0 = min(max(y0, 0), HH - 1), yc1 = min(max(y1, 0), HH - 1);
    int xc0 = min(max(x0, 0), WW - 1), xc1 = min(max(x1, 0), WW - 1);
    float w00 = (1.f - ly) * (1.f - lx) * m;
    float w01 = (1.f - ly) * lx * m;
    float w10 = ly * (1.f - lx) * m;
    float w11 = ly * lx * m;
    int4 iv; iv.x = yc0 * WW + xc0; iv.y = yc0 * WW + xc1; iv.z = yc1 * WW + xc0; iv.w = yc1 * WW + xc1;
    float4 wv;
    wv.x = (vy0 && vx0) ? w00 : 0.f;
    wv.y = (vy0 && vx1) ? w01 : 0.f;
    wv.z = (vy1 && vx0) ? w10 : 0.f;
    wv.w = (vy1 && vx1) ? w11 : 0.f;
    tbi[(size_t)t * MTOT + p] = iv;
    tbw[(size_t)t * MTOT + p] = wv;
}

// ---------------- implicit GEMM, lane=pixel gather ----------------
// Block = 64 pixels. Staging: wave w gathers channels cc*32+w*8..+7 for all 64
// pixels (lane = pixel) -> coalesced row loads. A through dbuf LDS; B fragments
// loaded per-lane direct from wq (reg double-buffer). One raw s_barrier/phase.
template<int NOCH, int NCOR, int WM, int WN, bool PASS2>
__global__ __launch_bounds__(256, 2) void gemm_dcn(
    const float* __restrict__ x,
    const unsigned short* __restrict__ wq,
    const int4* __restrict__ tbi, const float4* __restrict__ tbw,
    const float* __restrict__ ep0, const float* __restrict__ ep1,
    float* __restrict__ outp)
{
    constexpr int NWM = 4 / WM;
    __shared__ __align__(16) unsigned short Alds[2][64][40];

    const int tid  = threadIdx.x;
    const int wid  = tid >> 6;
    const int lane = tid & 63;
    const int l15  = lane & 15;
    const int kh   = lane >> 4;
    const int mslab = wid % NWM;
    const int nslab = wid / NWM;

    const int bid  = blockIdx.x;
    const int mblk = (bid & 7) * ((int)gridDim.x >> 3) + (bid >> 3);
    const int p0   = mblk * 64;

    const int pg   = p0 + lane;           // this lane's pixel
    const int img  = p0 / HWsz;           // uniform per block
    const int hw0  = pg - img * HWsz;
    const int ph   = hw0 / WW;
    const int pxx  = hw0 - ph * WW;
    const float* __restrict__ xim = x + (size_t)img * CCH * HWsz;

    f32x4 acc[WM][WN];
    #pragma unroll
    for (int m = 0; m < WM; ++m)
        #pragma unroll
        for (int n = 0; n < WN; ++n)
            acc[m][n] = f32x4{0.f, 0.f, 0.f, 0.f};

    // per-tap table registers (lane = pixel)
    int ti0 = 0, ti1 = 0, ti2 = 0, ti3 = 0;
    float tw0 = 0.f, tw1 = 0.f, tw2 = 0.f, tw3 = 0.f;
    float xv0[8], xv1[8], xv2[8], xv3[8];
    short8 bcur[WN], bnxt[WN];

    auto LOADTAB = [&](int t) {
        if constexpr (NCOR == 4) {
            int4 iv = tbi[(size_t)t * MTOT + pg];
            float4 wv = tbw[(size_t)t * MTOT + pg];
            ti0 = iv.x; ti1 = iv.y; ti2 = iv.z; ti3 = iv.w;
            tw0 = wv.x; tw1 = wv.y; tw2 = wv.z; tw3 = wv.w;
        } else {
            int yy = ph + t / 3 - 1, xx = pxx + t % 3 - 1;
            bool v = (yy >= 0) && (yy < HH) && (xx >= 0) && (xx < WW);
            ti0 = v ? yy * WW + xx : 0;
            tw0 = v ? 1.f : 0.f;
        }
    };

    auto PRELOAD = [&](int t, int cc) {
        const unsigned cb = (unsigned)(cc * 32 + wid * 8) * HWsz;
        #pragma unroll
        for (int i = 0; i < 8; ++i) {
            unsigned o = cb + (unsigned)i * HWsz;
            xv0[i] = xim[o + ti0];
            if constexpr (NCOR == 4) {
                xv1[i] = xim[o + ti1];
                xv2[i] = xim[o + ti2];
                xv3[i] = xim[o + ti3];
            }
        }
        // B fragments for this phase, direct per-lane (16B contiguous)
        #pragma unroll
        for (int n = 0; n < WN; ++n) {
            int och = nslab * WN * 16 + n * 16 + l15;
            bnxt[n] = *(const short8*)(wq + (size_t)(((t * 8 + cc) * 4 + kh) * NOCH + och) * 8);
        }
    };

    auto PACK = [&](int buf) {
        short8 pk;
        #pragma unroll
        for (int i = 0; i < 8; ++i) {
            float v = tw0 * xv0[i];
            if constexpr (NCOR == 4)
                v += tw1 * xv1[i] + tw2 * xv2[i] + tw3 * xv3[i];
            pk[i] = (short)f2bf(v);
        }
        *(short8*)&Alds[buf][lane][wid * 8] = pk;
    };

    LOADTAB(0);
    PRELOAD(0, 0);
    int buf = 0;
    for (int it = 0; it < NTAP * 8; ++it) {
        // B for current phase (loaded last iteration; vmcnt drain also covers
        // the gathers PACK is about to consume)
        #pragma unroll
        for (int n = 0; n < WN; ++n) bcur[n] = bnxt[n];
        PACK(buf);
        int nit = it + 1;
        if (nit < NTAP * 8) {
            int nt = nit >> 3, ncc = nit & 7;
            if (ncc == 0) LOADTAB(nt);
            PRELOAD(nt, ncc);
        }
        asm volatile("s_waitcnt lgkmcnt(0)" ::: "memory");
        __builtin_amdgcn_s_barrier();
        __builtin_amdgcn_sched_barrier(0);
        short8 af[WM];
        #pragma unroll
        for (int m = 0; m < WM; ++m)
            af[m] = *(const short8*)&Alds[buf][mslab * WM * 16 + m * 16 + l15][kh * 8];
        #pragma unroll
        for (int m = 0; m < WM; ++m)
            #pragma unroll
            for (int n = 0; n < WN; ++n)
                acc[m][n] = __builtin_amdgcn_mfma_f32_16x16x32_bf16(af[m], bcur[n], acc[m][n], 0, 0, 0);
        buf ^= 1;
    }

    // ---- epilogue (float4 stores) ----
    const int ohwb = p0 - img * HWsz;
    #pragma unroll
    for (int n = 0; n < WN; ++n) {
        int och = nslab * WN * 16 + n * 16 + l15;
        float s0 = 0.f, s1 = 0.f;
        if constexpr (PASS2) { s0 = ep0[och]; s1 = ep1[och]; }
        else { s1 = (och < 27) ? ep0[och] : 0.f; }
        #pragma unroll
        for (int m = 0; m < WM; ++m) {
            int ohw = ohwb + mslab * WM * 16 + m * 16 + kh * 4;
            float4 vv;
            if constexpr (PASS2) {
                vv.x = fmaxf(fmaf(acc[m][n][0], s0, s1), 0.f);
                vv.y = fmaxf(fmaf(acc[m][n][1], s0, s1), 0.f);
                vv.z = fmaxf(fmaf(acc[m][n][2], s0, s1), 0.f);
                vv.w = fmaxf(fmaf(acc[m][n][3], s0, s1), 0.f);
                *(float4*)&outp[((size_t)img * OO + och) * HWsz + ohw] = vv;
            } else {
                if (och < 27) {
                    vv.x = acc[m][n][0] + s1;
                    vv.y = acc[m][n][1] + s1;
                    vv.z = acc[m][n][2] + s1;
                    vv.w = acc[m][n][3] + s1;
                    *(float4*)&outp[((size_t)img * 32 + och) * HWsz + ohw] = vv;
                }
            }
        }
    }
}

extern "C" void kernel_launch(void* const* d_in, const int* in_sizes, int n_in,
                              void* d_out, int out_size, void* d_ws, size_t ws_size,
                              hipStream_t stream) {
    const float* input_x = (const float*)d_in[0];
    const float* w_off   = (const float*)d_in[1];
    const float* b_off   = (const float*)d_in[2];
    const float* w       = (const float*)d_in[3];
    const float* b       = (const float*)d_in[4];
    const float* gamma   = (const float*)d_in[5];
    const float* beta    = (const float*)d_in[6];
    const float* rmean   = (const float*)d_in[7];
    const float* rvar    = (const float*)d_in[8];
    float* out = (float*)d_out;

    char* p = (char*)d_ws;
    auto alloc = [&](size_t bytes) {
        char* r = p;
        p += (bytes + 255) & ~(size_t)255;
        return r;
    };
    unsigned short* wq  = (unsigned short*)alloc(589824 * 2);
    unsigned short* wqA = (unsigned short*)alloc(73728 * 2);
    int4*   tdi = (int4*)alloc((size_t)331776 * 16);
    float4* tdw = (float4*)alloc((size_t)331776 * 16);
    float* offb = (float*)alloc((size_t)4 * 32 * 9216 * 4);
    float* sc2 = (float*)alloc(256 * 4);
    float* sh2 = (float*)alloc(256 * 4);

    prep_kernel<<<2593, 256, 0, stream>>>(w, w_off, gamma, beta, rmean, rvar, b,
                                          wq, wqA, sc2, sh2);
    gemm_dcn<32, 1, 1, 2, false><<<576, 256, 0, stream>>>(input_x, wqA, nullptr, nullptr, b_off, nullptr, offb);
    build_table<<<1296, 256, 0, stream>>>(offb, tdi, tdw);
    gemm_dcn<256, 4, 4, 4, true><<<576, 256, 0, stream>>>(input_x, wq, tdi, tdw, sc2, sh2, out);
}